// Round 1
// baseline (106.639 us; speedup 1.0000x reference)
//
#include <hip/hip_runtime.h>
#include <hip/hip_bf16.h>

// ProductLayer: B=4096, F=32, D=64, U=256
// out[:,   0:256] = lz       = E[B,2048]    @ W1[2048,256]
// out[:, 256:512] = lp_inner = G[B,1024]    @ V [1024,256]   (G_b = E_b E_b^T gram)
// out[:, 512:768] = lp_outer = M[B,4096]    @ W2[4096,256]   (M_b = fs fs^T)
// A = [E | G | M] bf16 [4096, 7168], Wt = bf16 [256, 7168] (N-major for ds_read_b128)

#define KTOT 7168

typedef __attribute__((ext_vector_type(8))) short short8v;
typedef __attribute__((ext_vector_type(4))) float f32x4;

static __device__ __forceinline__ short f2bf(float f) {
    union { float f; unsigned u; } v; v.f = f;
    unsigned r = v.u + 0x7fffu + ((v.u >> 16) & 1u);  // RNE
    return (short)(r >> 16);
}

// ---------------- prep A: one block per batch row ----------------
__global__ __launch_bounds__(256) void prep_a(const float* __restrict__ embeds,
                                              short* __restrict__ A) {
    int b = blockIdx.x;
    const float* e = embeds + (size_t)b * 2048;
    short* arow = A + (size_t)b * KTOT;
    __shared__ float se[2048];     // fp32 row [32][64]
    __shared__ short sebf[2048];   // bf16 row [32][64]
    __shared__ float fs[64];
    int t = threadIdx.x;

    float4 v0 = ((const float4*)e)[t * 2];
    float4 v1 = ((const float4*)e)[t * 2 + 1];
    ((float4*)se)[t * 2] = v0;
    ((float4*)se)[t * 2 + 1] = v1;
    short8v sb;
    sb[0] = f2bf(v0.x); sb[1] = f2bf(v0.y); sb[2] = f2bf(v0.z); sb[3] = f2bf(v0.w);
    sb[4] = f2bf(v1.x); sb[5] = f2bf(v1.y); sb[6] = f2bf(v1.z); sb[7] = f2bf(v1.w);
    ((short8v*)sebf)[t] = sb;
    *(short8v*)&arow[t * 8] = sb;   // E segment

    __syncthreads();
    if (t < 64) {
        float s = 0.f;
        #pragma unroll
        for (int f = 0; f < 32; ++f) s += se[f * 64 + t];
        fs[t] = s;
    }
    __syncthreads();

    // G = E E^T via MFMA: 4 waves, one 16x16 tile each, K=64 in 2 steps
    int wid = t >> 6, lane = t & 63;
    int tm = wid >> 1, tn = wid & 1;
    int lr = lane & 15, lk = (lane >> 4) * 8;
    f32x4 g = {0.f, 0.f, 0.f, 0.f};
    #pragma unroll
    for (int ks = 0; ks < 2; ++ks) {
        short8v a  = *(const short8v*)&sebf[(tm * 16 + lr) * 64 + ks * 32 + lk];
        short8v bb = *(const short8v*)&sebf[(tn * 16 + lr) * 64 + ks * 32 + lk];
        g = __builtin_amdgcn_mfma_f32_16x16x32_bf16(a, bb, g, 0, 0, 0);
    }
    #pragma unroll
    for (int r = 0; r < 4; ++r) {
        int grow = tm * 16 + (lane >> 4) * 4 + r;  // C/D: col=lane&15, row=(lane>>4)*4+r
        int gcol = tn * 16 + lr;
        arow[2048 + grow * 32 + gcol] = f2bf(g[r]);
    }

    // M = fs fs^T (fp32 fs, bf16 products). thread -> (i = t/4, 16 j's)
    {
        int i = t >> 2;
        int j0 = (t & 3) * 16;
        float fi = fs[i];
        short8v m0, m1;
        #pragma unroll
        for (int r = 0; r < 8; ++r) m0[r] = f2bf(fi * fs[j0 + r]);
        #pragma unroll
        for (int r = 0; r < 8; ++r) m1[r] = f2bf(fi * fs[j0 + 8 + r]);
        *(short8v*)&arow[3072 + i * 64 + j0] = m0;
        *(short8v*)&arow[3072 + i * 64 + j0 + 8] = m1;
    }
}

// ---------------- prep W: one block per unit u ----------------
__global__ __launch_bounds__(256) void prep_w(const float* __restrict__ lw,
                                              const float* __restrict__ iw,
                                              const float* __restrict__ ow,
                                              short* __restrict__ Wt) {
    int u = blockIdx.x;
    int t = threadIdx.x;
    short* w = Wt + (size_t)u * KTOT;

    // linear_w transpose column u (uncoalesced reads, L2-absorbed: 2 MB total)
    for (int k = t; k < 2048; k += 256) w[k] = f2bf(lw[(size_t)k * 256 + u]);

    __shared__ float wi[32];
    if (t < 32) wi[t] = iw[u * 32 + t];
    __syncthreads();
    for (int idx = t; idx < 1024; idx += 256)
        w[2048 + idx] = f2bf(wi[idx >> 5] * wi[idx & 31]);

    // outer_w[u] flat copy (coalesced), 4096 floats -> 512 x short8
    const float* owu = ow + (size_t)u * 4096;
    for (int i = t; i < 512; i += 256) {
        float4 a = ((const float4*)owu)[i * 2];
        float4 b = ((const float4*)owu)[i * 2 + 1];
        short8v s;
        s[0] = f2bf(a.x); s[1] = f2bf(a.y); s[2] = f2bf(a.z); s[3] = f2bf(a.w);
        s[4] = f2bf(b.x); s[5] = f2bf(b.y); s[6] = f2bf(b.z); s[7] = f2bf(b.w);
        *(short8v*)&w[3072 + i * 8] = s;
    }
}

// ---------------- GEMM: 128x128 tile, BK=64, m97 structure ----------------
__global__ __launch_bounds__(256) void gemm_seg(const short* __restrict__ A,
                                                const short* __restrict__ Wt,
                                                float* __restrict__ out) {
    __shared__ short As[128 * 64];
    __shared__ short Bs[128 * 64];
    int seg = blockIdx.z;
    int k_off = (seg == 0) ? 0 : (seg == 1) ? 2048 : 3072;
    int K     = (seg == 0) ? 2048 : (seg == 1) ? 1024 : 4096;
    int brow = blockIdx.x * 128;
    int bcol = blockIdx.y * 128;

    int t = threadIdx.x;
    int wid = t >> 6, lane = t & 63;
    int wr = wid >> 1, wc = wid & 1;
    int lr = lane & 15, lk = (lane >> 4) * 8;

    const short* Ag = A  + (size_t)(brow + (t >> 3)) * KTOT + k_off + (t & 7) * 8;
    const short* Bg = Wt + (size_t)(bcol + (t >> 3)) * KTOT + k_off + (t & 7) * 8;

    f32x4 acc[4][4];
    #pragma unroll
    for (int m = 0; m < 4; ++m)
        #pragma unroll
        for (int n = 0; n < 4; ++n) acc[m][n] = (f32x4){0.f, 0.f, 0.f, 0.f};

    for (int kt = 0; kt < K; kt += 64) {
        __syncthreads();
        #pragma unroll
        for (int i = 0; i < 4; ++i) {
            __builtin_amdgcn_global_load_lds(
                (const __attribute__((address_space(1))) void*)(Ag + (size_t)i * 32 * KTOT + kt),
                (__attribute__((address_space(3))) void*)(As + i * 2048 + wid * 512),
                16, 0, 0);
            __builtin_amdgcn_global_load_lds(
                (const __attribute__((address_space(1))) void*)(Bg + (size_t)i * 32 * KTOT + kt),
                (__attribute__((address_space(3))) void*)(Bs + i * 2048 + wid * 512),
                16, 0, 0);
        }
        __syncthreads();
        #pragma unroll
        for (int ks = 0; ks < 2; ++ks) {
            short8v a[4], bb[4];
            #pragma unroll
            for (int m = 0; m < 4; ++m)
                a[m] = *(const short8v*)&As[(wr * 64 + m * 16 + lr) * 64 + ks * 32 + lk];
            #pragma unroll
            for (int n = 0; n < 4; ++n)
                bb[n] = *(const short8v*)&Bs[(wc * 64 + n * 16 + lr) * 64 + ks * 32 + lk];
            #pragma unroll
            for (int m = 0; m < 4; ++m)
                #pragma unroll
                for (int n = 0; n < 4; ++n)
                    acc[m][n] = __builtin_amdgcn_mfma_f32_16x16x32_bf16(a[m], bb[n], acc[m][n], 0, 0, 0);
        }
    }

    int col0 = seg * 256 + bcol + wc * 64;
    int row0 = brow + wr * 64;
    #pragma unroll
    for (int m = 0; m < 4; ++m)
        #pragma unroll
        for (int n = 0; n < 4; ++n)
            #pragma unroll
            for (int r = 0; r < 4; ++r) {
                int row = row0 + m * 16 + (lane >> 4) * 4 + r;
                int col = col0 + n * 16 + lr;
                out[(size_t)row * 768 + col] = acc[m][n][r];
            }
}

extern "C" void kernel_launch(void* const* d_in, const int* in_sizes, int n_in,
                              void* d_out, int out_size, void* d_ws, size_t ws_size,
                              hipStream_t stream) {
    const float* embeds = (const float*)d_in[0];
    const float* lw = (const float*)d_in[1];
    const float* iw = (const float*)d_in[2];
    const float* ow = (const float*)d_in[3];
    float* out = (float*)d_out;

    short* A  = (short*)d_ws;                    // 4096*7168*2 = 58,720,256 B
    short* Wt = A + (size_t)4096 * KTOT;         // + 256*7168*2 = 3,670,016 B

    prep_a<<<dim3(4096), dim3(256), 0, stream>>>(embeds, A);
    prep_w<<<dim3(256), dim3(256), 0, stream>>>(lw, iw, ow, Wt);
    gemm_seg<<<dim3(32, 2, 3), dim3(256), 0, stream>>>(A, Wt, out);
}

// Round 2
// 95.339 us; speedup vs baseline: 1.1185x; 1.1185x over previous
//
#include <hip/hip_runtime.h>
#include <hip/hip_bf16.h>

// ProductLayer: B=4096, F=32, D=64, U=256
// out[:,   0:256] = lz       = E[B,2048]    @ W1[2048,256]
// out[:, 256:512] = lp_inner = G[B,1024]    @ V [1024,256]   (G_b = E_b E_b^T gram)
// out[:, 512:768] = lp_outer = M[B,4096]    @ W2[4096,256]   (M_b = fs fs^T)
// A = [E | G | M] bf16 [4096, 7168], Wt = bf16 [256, 7168] (N-major for ds_read_b128)
// GEMM v2: split-K (KCHUNK=512) flattened into 896 equal blocks + fp32 atomic epilogue.

#define KTOT 7168
#define KCHUNK 512

typedef __attribute__((ext_vector_type(8))) short short8v;
typedef __attribute__((ext_vector_type(4))) float f32x4;

static __device__ __forceinline__ short f2bf(float f) {
    union { float f; unsigned u; } v; v.f = f;
    unsigned r = v.u + 0x7fffu + ((v.u >> 16) & 1u);  // RNE
    return (short)(r >> 16);
}

// ---------------- prep A: one block per batch row ----------------
__global__ __launch_bounds__(256) void prep_a(const float* __restrict__ embeds,
                                              short* __restrict__ A) {
    int b = blockIdx.x;
    const float* e = embeds + (size_t)b * 2048;
    short* arow = A + (size_t)b * KTOT;
    __shared__ float se[2048];     // fp32 row [32][64]
    __shared__ short sebf[2048];   // bf16 row [32][64]
    __shared__ float fs[64];
    int t = threadIdx.x;

    float4 v0 = ((const float4*)e)[t * 2];
    float4 v1 = ((const float4*)e)[t * 2 + 1];
    ((float4*)se)[t * 2] = v0;
    ((float4*)se)[t * 2 + 1] = v1;
    short8v sb;
    sb[0] = f2bf(v0.x); sb[1] = f2bf(v0.y); sb[2] = f2bf(v0.z); sb[3] = f2bf(v0.w);
    sb[4] = f2bf(v1.x); sb[5] = f2bf(v1.y); sb[6] = f2bf(v1.z); sb[7] = f2bf(v1.w);
    ((short8v*)sebf)[t] = sb;
    *(short8v*)&arow[t * 8] = sb;   // E segment

    __syncthreads();
    if (t < 64) {
        float s = 0.f;
        #pragma unroll
        for (int f = 0; f < 32; ++f) s += se[f * 64 + t];
        fs[t] = s;
    }
    __syncthreads();

    // G = E E^T via MFMA: 4 waves, one 16x16 tile each, K=64 in 2 steps
    int wid = t >> 6, lane = t & 63;
    int tm = wid >> 1, tn = wid & 1;
    int lr = lane & 15, lk = (lane >> 4) * 8;
    f32x4 g = {0.f, 0.f, 0.f, 0.f};
    #pragma unroll
    for (int ks = 0; ks < 2; ++ks) {
        short8v a  = *(const short8v*)&sebf[(tm * 16 + lr) * 64 + ks * 32 + lk];
        short8v bb = *(const short8v*)&sebf[(tn * 16 + lr) * 64 + ks * 32 + lk];
        g = __builtin_amdgcn_mfma_f32_16x16x32_bf16(a, bb, g, 0, 0, 0);
    }
    #pragma unroll
    for (int r = 0; r < 4; ++r) {
        int grow = tm * 16 + (lane >> 4) * 4 + r;  // C/D: col=lane&15, row=(lane>>4)*4+r
        int gcol = tn * 16 + lr;
        arow[2048 + grow * 32 + gcol] = f2bf(g[r]);
    }

    // M = fs fs^T (fp32 fs, bf16 products). thread -> (i = t/4, 16 j's)
    {
        int i = t >> 2;
        int j0 = (t & 3) * 16;
        float fi = fs[i];
        short8v m0, m1;
        #pragma unroll
        for (int r = 0; r < 8; ++r) m0[r] = f2bf(fi * fs[j0 + r]);
        #pragma unroll
        for (int r = 0; r < 8; ++r) m1[r] = f2bf(fi * fs[j0 + 8 + r]);
        *(short8v*)&arow[3072 + i * 64 + j0] = m0;
        *(short8v*)&arow[3072 + i * 64 + j0 + 8] = m1;
    }
}

// ---------------- prep W: one block per unit u ----------------
__global__ __launch_bounds__(256) void prep_w(const float* __restrict__ lw,
                                              const float* __restrict__ iw,
                                              const float* __restrict__ ow,
                                              short* __restrict__ Wt) {
    int u = blockIdx.x;
    int t = threadIdx.x;
    short* w = Wt + (size_t)u * KTOT;

    // linear_w transpose column u (uncoalesced reads, L2-absorbed: 2 MB total)
    for (int k = t; k < 2048; k += 256) w[k] = f2bf(lw[(size_t)k * 256 + u]);

    __shared__ float wi[32];
    if (t < 32) wi[t] = iw[u * 32 + t];
    __syncthreads();
    for (int idx = t; idx < 1024; idx += 256)
        w[2048 + idx] = f2bf(wi[idx >> 5] * wi[idx & 31]);

    // outer_w[u] flat copy (coalesced), 4096 floats -> 512 x short8
    const float* owu = ow + (size_t)u * 4096;
    for (int i = t; i < 512; i += 256) {
        float4 a = ((const float4*)owu)[i * 2];
        float4 b = ((const float4*)owu)[i * 2 + 1];
        short8v s;
        s[0] = f2bf(a.x); s[1] = f2bf(a.y); s[2] = f2bf(a.z); s[3] = f2bf(a.w);
        s[4] = f2bf(b.x); s[5] = f2bf(b.y); s[6] = f2bf(b.z); s[7] = f2bf(b.w);
        *(short8v*)&w[3072 + i * 8] = s;
    }
}

// ---------------- GEMM: 128x128x512 work units, flat 896-block grid ----------------
// seg0: 256 blocks (32 mt x 2 nt x 4 kc), seg1: 128 (x2 kc), seg2: 512 (x8 kc)
__global__ __launch_bounds__(256) void gemm_seg(const short* __restrict__ A,
                                                const short* __restrict__ Wt,
                                                float* __restrict__ out) {
    __shared__ short As[128 * 64];
    __shared__ short Bs[128 * 64];

    int id = blockIdx.x;
    int seg, mt, nt, kc;
    if (id < 256)      { seg = 0; kc = id & 3; nt = (id >> 2) & 1; mt = id >> 3; }
    else if (id < 384) { int b = id - 256; seg = 1; kc = b & 1; nt = (b >> 1) & 1; mt = b >> 2; }
    else               { int b = id - 384; seg = 2; kc = b & 7; nt = (b >> 3) & 1; mt = b >> 4; }
    int seg_base = (seg == 0) ? 0 : (seg == 1) ? 2048 : 3072;
    int k_off = seg_base + kc * KCHUNK;
    int brow = mt * 128;
    int bcol = nt * 128;

    int t = threadIdx.x;
    int wid = t >> 6, lane = t & 63;
    int wr = wid >> 1, wc = wid & 1;
    int lr = lane & 15, lk = (lane >> 4) * 8;

    const short* Ag = A  + (size_t)(brow + (t >> 3)) * KTOT + k_off + (t & 7) * 8;
    const short* Bg = Wt + (size_t)(bcol + (t >> 3)) * KTOT + k_off + (t & 7) * 8;

    f32x4 acc[4][4];
    #pragma unroll
    for (int m = 0; m < 4; ++m)
        #pragma unroll
        for (int n = 0; n < 4; ++n) acc[m][n] = (f32x4){0.f, 0.f, 0.f, 0.f};

    for (int kt = 0; kt < KCHUNK; kt += 64) {
        __syncthreads();
        #pragma unroll
        for (int i = 0; i < 4; ++i) {
            __builtin_amdgcn_global_load_lds(
                (const __attribute__((address_space(1))) void*)(Ag + (size_t)i * 32 * KTOT + kt),
                (__attribute__((address_space(3))) void*)(As + i * 2048 + wid * 512),
                16, 0, 0);
            __builtin_amdgcn_global_load_lds(
                (const __attribute__((address_space(1))) void*)(Bg + (size_t)i * 32 * KTOT + kt),
                (__attribute__((address_space(3))) void*)(Bs + i * 2048 + wid * 512),
                16, 0, 0);
        }
        __syncthreads();
        #pragma unroll
        for (int ks = 0; ks < 2; ++ks) {
            short8v a[4], bb[4];
            #pragma unroll
            for (int m = 0; m < 4; ++m)
                a[m] = *(const short8v*)&As[(wr * 64 + m * 16 + lr) * 64 + ks * 32 + lk];
            #pragma unroll
            for (int n = 0; n < 4; ++n)
                bb[n] = *(const short8v*)&Bs[(wc * 64 + n * 16 + lr) * 64 + ks * 32 + lk];
            #pragma unroll
            for (int m = 0; m < 4; ++m)
                #pragma unroll
                for (int n = 0; n < 4; ++n)
                    acc[m][n] = __builtin_amdgcn_mfma_f32_16x16x32_bf16(a[m], bb[n], acc[m][n], 0, 0, 0);
        }
    }

    int col0 = seg * 256 + bcol + wc * 64;
    int row0 = brow + wr * 64;
    #pragma unroll
    for (int m = 0; m < 4; ++m)
        #pragma unroll
        for (int n = 0; n < 4; ++n)
            #pragma unroll
            for (int r = 0; r < 4; ++r) {
                int row = row0 + m * 16 + (lane >> 4) * 4 + r;
                int col = col0 + n * 16 + lr;
                unsafeAtomicAdd(&out[(size_t)row * 768 + col], acc[m][n][r]);
            }
}

extern "C" void kernel_launch(void* const* d_in, const int* in_sizes, int n_in,
                              void* d_out, int out_size, void* d_ws, size_t ws_size,
                              hipStream_t stream) {
    const float* embeds = (const float*)d_in[0];
    const float* lw = (const float*)d_in[1];
    const float* iw = (const float*)d_in[2];
    const float* ow = (const float*)d_in[3];
    float* out = (float*)d_out;

    short* A  = (short*)d_ws;                    // 4096*7168*2 = 58,720,256 B
    short* Wt = A + (size_t)4096 * KTOT;         // + 256*7168*2 = 3,670,016 B

    prep_a<<<dim3(4096), dim3(256), 0, stream>>>(embeds, A);
    prep_w<<<dim3(256), dim3(256), 0, stream>>>(lw, iw, ow, Wt);
    hipMemsetAsync(out, 0, (size_t)out_size * sizeof(float), stream);
    gemm_seg<<<dim3(896), dim3(256), 0, stream>>>(A, Wt, out);
}